// Round 10
// baseline (331.772 us; speedup 1.0000x reference)
//
#include <hip/hip_runtime.h>
#include <hip/hip_bf16.h>
#include <stdint.h>

typedef __attribute__((ext_vector_type(8))) short short8;
typedef __attribute__((ext_vector_type(4))) short short4v;
typedef __attribute__((ext_vector_type(4))) float floatx4;
typedef __attribute__((ext_vector_type(2))) float floatx2;
typedef __attribute__((ext_vector_type(2))) int intx2;
typedef __hip_bfloat16 bf16;

__device__ __forceinline__ float b2f(bf16 v) { return __bfloat162float(v); }
__device__ __forceinline__ bf16 f2b(float v) { return __float2bfloat16(v); }
__device__ __forceinline__ float gelu_f(float v) {
    return 0.5f * v * (1.0f + erff(v * 0.70710678118654752f));
}
// two packed bf16 (one dword) -> two fp32, exact (<<16)
__device__ __forceinline__ floatx2 cvt2(unsigned v) {
    floatx2 r;
    r.x = __uint_as_float(v << 16);
    r.y = __uint_as_float(v & 0xffff0000u);
    return r;
}
// VALU-rate cross-lane add via DPP (no LGKM). CTRL: 0xB1=quad xor1, 0x4E=quad xor2,
// 0x141=row_half_mirror (cross-quad within 8-lane group; groups are 8-aligned).
template <int CTRL>
__device__ __forceinline__ float dpp_add(float v) {
    int x = __builtin_amdgcn_update_dpp(0, __float_as_int(v), CTRL, 0xf, 0xf, true);
    return v + __int_as_float(x);
}
// full-wave half sum at VALU rate: v[l] + v[l^32] for every lane.
__device__ __forceinline__ float sum_halves(float v) {
#if __has_builtin(__builtin_amdgcn_permlane32_swap)
    intx2 r = __builtin_amdgcn_permlane32_swap(__float_as_int(v), __float_as_int(v),
                                               false, false);
    return __int_as_float(r.x) + __int_as_float(r.y);
#else
    return v + __shfl_xor(v, 32, 64);
#endif
}

#define GLD_LDS16(gptr, lptr) \
  __builtin_amdgcn_global_load_lds((const __attribute__((address_space(1))) void*)(gptr), \
                                   (__attribute__((address_space(3))) void*)(lptr), 16, 0, 0)

// NOTE (R12): cooperative grid.sync() costs ~60us each here -- never fuse via grid.sync.
// NOTE (R15): GEMM LDS conflicts: fragment reads, fixed by XOR-swizzled 16B chunks
// (physical slot = logical ^ (row&7)); global_load_lds dest is linear, so swizzle the
// SOURCE k-offset.
// NOTE (R16): x pre-converted to bf16; GEMM = bf16 global_load_lds path; GEMM epilogue
// in two 64-row halves -> LDS exactly 32 KB.
// NOTE (R17/R20b, FAILED): extra per-lane state in k_agg loop (prefetch regs or
// 16ch/lane) kills it -- occupancy/ILP loss > latency gain.
// NOTE (R18, FAILED): node-grain work-steal = 32768 same-address atomics = 460us wall.
// NOTE (R19): 128-thread blocks; k_agg is instruction-issue-bound (VALU ~74%).
// NOTE (R21): leaky=max(u,0.2u); att pre-scaled by log2e -> raw v_exp_f32. KEEP.
// NOTE (R22/R23): bucket CSR (atomic return IS the slot) deletes scan/rank; scatter
// MUST stay overlapped with GEMM1 (standalone = 49us exposed latency). KEEP.
// NOTE (R24, FAILED-codegen): passing gather arrays as const unsigned* to a lambda
// took their address -> AMDGPU promote-alloca put them in LDS (LDS_Block_Size=4096,
// 1.97M bank conflicts, VALU 74->55%). NEVER pass register arrays by pointer.
// NOTE (R25): same unroll + 4/4 epilogue split, but proc takes 4 scalars by value and
// buffers are named uint4 values -- no address escape, buffers stay in VGPRs.

// ---------------- pre-pass: weight transposes (0..1023) + x->bf16 (1024..2047) + cnt=0 ----------------
__global__ void k_tr(const float* __restrict__ Wl1, const float* __restrict__ Wr1,
                     const float* __restrict__ Wl2, const float* __restrict__ Wr2,
                     bf16* __restrict__ Wt,
                     const float* __restrict__ x, bf16* __restrict__ xb,
                     int* __restrict__ cnt) {
    int bx = blockIdx.x;
    if (bx < 1024) {
        int r = bx & 255, half = (bx >> 8) & 1, layer = bx >> 9;
        int c = threadIdx.x;
        const float* W = layer ? (half ? Wr2 : Wl2) : (half ? Wr1 : Wl1);
        Wt[(size_t)(layer * 512 + half * 256 + c) * 256 + r] = f2b(W[r * 256 + c]);
    } else if (bx < 2048) {
        // x (32768x256 fp32) -> bf16, 32 contiguous floats per thread
        int b = bx - 1024;
        size_t base = ((size_t)b * 256 + threadIdx.x) * 32;
        const float4* xin = (const float4*)(x + base);
        #pragma unroll
        for (int q = 0; q < 4; q++) {
            float4 a = xin[2 * q];
            float4 c = xin[2 * q + 1];
            bf16 t[8] = {f2b(a.x), f2b(a.y), f2b(a.z), f2b(a.w),
                         f2b(c.x), f2b(c.y), f2b(c.z), f2b(c.w)};
            *(short8*)(xb + base + q * 8) = *(const short8*)t;
        }
    } else {
        // zero cnt (32768 ints; 128 blocks x 256 threads)
        cnt[(bx - 2048) * 256 + threadIdx.x] = 0;
    }
}

// ---------------- GEMM tile body: C[M,512] = A[M,K] @ Bt[512,K]^T + bias ----------------
// 128x128 tile, BK=64, XOR-swizzled LDS (physical 16B chunk = logical ^ (row&7)).
// bf16 A only (global_load_lds both operands). LDS = 32768 B exactly (5 blocks/CU).
__device__ __forceinline__ void gemm_body(const bf16* __restrict__ A,
                                          const bf16* __restrict__ Bt,
                                          const float* __restrict__ biasL,
                                          const float* __restrict__ biasR,
                                          bf16* __restrict__ C,
                                          int K, int m0, int n0,
                                          bf16* __restrict__ smem) {
    bf16* As = smem;
    bf16* Bs = smem + 8192;
    const int tid  = threadIdx.x;
    const int wave = tid >> 6;
    const int lane = tid & 63;
    const int quad = lane >> 4;
    const int l16  = lane & 15;
    const int wm = (wave & 1) * 64;
    const int wn = (wave >> 1) * 64;
    // source k-offset for swizzled global_load_lds staging (dest slot lane&7, row lane>>3)
    const int scole = ((lane & 7) ^ (lane >> 3)) * 8;
    const int srow  = lane >> 3;

    floatx4 acc[4][4] = {};

    for (int k0 = 0; k0 < K; k0 += 64) {
        #pragma unroll
        for (int i = 0; i < 4; i++) {
            int chunk = i * 4 + wave;                 // 16 chunks of 1 KB (8 rows) each
            int row = chunk * 8 + srow;
            GLD_LDS16(A + (size_t)(m0 + row) * K + k0 + scole,
                      (char*)As + chunk * 1024 + lane * 16);
            GLD_LDS16(Bt + (size_t)(n0 + row) * K + k0 + scole,
                      (char*)Bs + chunk * 1024 + lane * 16);
        }
        __syncthreads();
        #pragma unroll
        for (int ks = 0; ks < 2; ks++) {
            short8 af[4], bfr[4];
            int pk = ((ks * 4 + quad) ^ (l16 & 7)) * 8;   // swizzled fragment k-offset
            #pragma unroll
            for (int i = 0; i < 4; i++) {
                af[i]  = *(const short8*)&As[(wm + i * 16 + l16) * 64 + pk];
                bfr[i] = *(const short8*)&Bs[(wn + i * 16 + l16) * 64 + pk];
            }
            #pragma unroll
            for (int i = 0; i < 4; i++)
                #pragma unroll
                for (int j = 0; j < 4; j++)
                    acc[i][j] = __builtin_amdgcn_mfma_f32_16x16x32_bf16(af[i], bfr[j], acc[i][j], 0, 0, 0);
        }
        __syncthreads();
    }

    // C/D layout: col = lane&15, row = quad*4 + reg  [verified m89/m91]
    // Two 64-row halves through a 64x136 LDS buffer (fits in As+Bs region).
    float bvj[4];
    #pragma unroll
    for (int j = 0; j < 4; j++) {
        int gcol = n0 + wn + j * 16 + l16;
        bvj[j] = (gcol < 256) ? biasL[gcol] : biasR[gcol - 256];
    }
    #pragma unroll
    for (int h = 0; h < 2; h++) {
        if ((wave & 1) == h) {
            #pragma unroll
            for (int j = 0; j < 4; j++) {
                int lcol = wn + j * 16 + l16;
                #pragma unroll
                for (int i = 0; i < 4; i++)
                    #pragma unroll
                    for (int r = 0; r < 4; r++)
                        smem[(i * 16 + quad * 4 + r) * 136 + lcol] = f2b(acc[i][j][r] + bvj[j]);
            }
        }
        __syncthreads();
        {
            int rl = tid >> 4;
            int cs = (tid & 15) * 8;
            #pragma unroll
            for (int p = 0; p < 4; p++) {
                int row = p * 16 + rl;
                short8 v = *(const short8*)&smem[row * 136 + cs];
                *(short8*)(C + (size_t)(m0 + h * 64 + row) * 512 + n0 + cs) = v;
            }
        }
        if (h == 0) __syncthreads();
    }
}

// ---------------- union dispatch: bucket scatter + layer-1 GEMM (roles interleaved) ----------------
__global__ __launch_bounds__(256) void k_scatter_gemm(const int* __restrict__ src,
                                                      const int* __restrict__ dst,
                                                      int* __restrict__ cnt,
                                                      int* __restrict__ col, int E,
                                                      const bf16* __restrict__ A,
                                                      const bf16* __restrict__ Bt,
                                                      const float* __restrict__ biasL,
                                                      const float* __restrict__ biasR,
                                                      bf16* __restrict__ C, int K) {
    __shared__ bf16 smem[16384];
    int bx = blockIdx.x;
    int rem = bx % 3;
    if (rem == 2) {
        int g = (bx / 3) * 256 + threadIdx.x;
        if (g * 4 < E) {
            int4 d = ((const int4*)dst)[g];
            int4 s = ((const int4*)src)[g];
            int rk;
            rk = atomicAdd(&cnt[d.x], 1); if (rk < 64) col[(d.x << 6) + rk] = s.x;
            rk = atomicAdd(&cnt[d.y], 1); if (rk < 64) col[(d.y << 6) + rk] = s.y;
            rk = atomicAdd(&cnt[d.z], 1); if (rk < 64) col[(d.z << 6) + rk] = s.z;
            rk = atomicAdd(&cnt[d.w], 1); if (rk < 64) col[(d.w << 6) + rk] = s.w;
        }
    } else {
        int gid = (bx / 3) * 2 + rem;
        int n0 = (gid & 3) * 128;
        int m0 = (gid >> 2) * 128;
        gemm_body(A, Bt, biasL, biasR, C, K, m0, n0, smem);
    }
}

// ---------------- standalone GEMM (layer 2, bf16 A) ----------------
__global__ __launch_bounds__(256) void k_gemm2(const bf16* __restrict__ A,
                                               const bf16* __restrict__ Bt,
                                               const float* __restrict__ biasL,
                                               const float* __restrict__ biasR,
                                               bf16* __restrict__ C, int K) {
    __shared__ bf16 smem[16384];
    gemm_body(A, Bt, biasL, biasR, C, K, blockIdx.y * 128, blockIdx.x * 128, smem);
}

// ---------------- GATv2 aggregation: half-wave per edge, 8 ch/lane, packed fp32 math ----------
// 128-thread blocks, one wave per dst node. Lanes 0-31 = item a, 32-63 = item b of each
// pair. Within a half: 8 lanes per head (hl>>3), 8 channels per lane ((hl&7)*8).
// Item 0 = self-loop. Bucket CSR: node i's in-edges at col[i*64 .. i*64+deg).
// Max-free softmax (logits bounded). leaky = max(u, 0.2u); att pre-scaled by log2(e)
// so p = v_exp_f32(l) = e^logit. Reduce via DPP; half-combine via permlane32_swap.
// R25: 2x unroll with named uint4 buffers + scalar-by-value proc (no address escape);
// epilogue split 4/4 channels across halves.
__global__ __launch_bounds__(128) void k_agg(const bf16* __restrict__ xlr,
                                             const float* __restrict__ att,
                                             const int* __restrict__ cnt,
                                             const int* __restrict__ col,
                                             const float* __restrict__ bias,
                                             bf16* __restrict__ out, int do_gelu) {
    int wave = threadIdx.x >> 6, lane = threadIdx.x & 63;
    int i = blockIdx.x * 2 + wave;
    int hl = lane & 31;
    int half = lane >> 5;
    unsigned f = (hl >> 3) * 64 + (hl & 7) * 8;

    const float LOG2E = 1.4426950408889634f;
    const floatx2 c02 = {0.2f, 0.2f};
    floatx2 attv[4], xrv[4];
    {
        floatx4 a0 = *(const floatx4*)(att + f);
        floatx4 a1 = *(const floatx4*)(att + f + 4);
        attv[0] = (floatx2){LOG2E * a0[0], LOG2E * a0[1]};
        attv[1] = (floatx2){LOG2E * a0[2], LOG2E * a0[3]};
        attv[2] = (floatx2){LOG2E * a1[0], LOG2E * a1[1]};
        attv[3] = (floatx2){LOG2E * a1[2], LOG2E * a1[3]};
        unsigned raw0, raw1, raw2, raw3;
        uint4 rv = *(const uint4*)(xlr + ((unsigned)i * 512u + 256u + f));
        raw0 = rv.x; raw1 = rv.y; raw2 = rv.z; raw3 = rv.w;
        xrv[0] = cvt2(raw0); xrv[1] = cvt2(raw1);
        xrv[2] = cvt2(raw2); xrv[3] = cvt2(raw3);
    }

    int deg = cnt[i];
    deg = deg > 64 ? 64 : deg;
    int e0 = i << 6;
    int total = 1 + deg;   // self + in-edges

    // src index for item t (self=0, then in-edges); OOB clamps to i (safe dummy)
    auto item = [&](int t) -> int {
        return (t > 0 && t < total) ? col[e0 + t - 1] : i;
    };

    float s = 0.f;
    floatx2 acc2[4] = {};

    // scalar-by-value: no array address ever escapes (R24's LDS-promotion trap)
    auto proc = [&](unsigned g0, unsigned g1, unsigned g2, unsigned g3, bool valid) {
        floatx2 xv0 = cvt2(g0), xv1 = cvt2(g1), xv2 = cvt2(g2), xv3 = cvt2(g3);
        floatx2 l2 = {0.f, 0.f};
        floatx2 u, lr;
        u = xv0 + xrv[0]; lr = __builtin_elementwise_max(u, u * c02); l2 += lr * attv[0];
        u = xv1 + xrv[1]; lr = __builtin_elementwise_max(u, u * c02); l2 += lr * attv[1];
        u = xv2 + xrv[2]; lr = __builtin_elementwise_max(u, u * c02); l2 += lr * attv[2];
        u = xv3 + xrv[3]; lr = __builtin_elementwise_max(u, u * c02); l2 += lr * attv[3];
        float l = l2.x + l2.y;
        l = dpp_add<0xB1>(l);     // xor1 within quad
        l = dpp_add<0x4E>(l);     // xor2 within quad
        l = dpp_add<0x141>(l);    // cross-quad within 8-lane group
        float p;
        asm("v_exp_f32 %0, %1" : "=v"(p) : "v"(l));   // e^logit (att pre-scaled)
        p = valid ? p : 0.f;
        s += p;
        floatx2 p2 = {p, p};
        acc2[0] += p2 * xv0;
        acc2[1] += p2 * xv1;
        acc2[2] += p2 * xv2;
        acc2[3] += p2 * xv3;
    };

    // 2x-unrolled pair loop: named uint4 buffers swap roles (no rotation movs).
    // Data prefetch 1 pair ahead, index 2 pairs ahead (same depth as R19-R23).
    int sA = item(half);          // pair 0
    uint4 gA = *(const uint4*)(xlr + ((unsigned)sA * 512u + f));
    int sB = item(2 + half);      // pair 1 idx
    uint4 gB;

    for (int base = 0; base < total; base += 4) {
        gB = *(const uint4*)(xlr + ((unsigned)sB * 512u + f));   // pair+1 data
        sA = item(base + 4 + half);                              // pair+2 idx
        proc(gA.x, gA.y, gA.z, gA.w, (base + half) < total);
        gA = *(const uint4*)(xlr + ((unsigned)sA * 512u + f));   // pair+2 data
        sB = item(base + 6 + half);                              // pair+3 idx
        proc(gB.x, gB.y, gB.z, gB.w, (base + 2 + half) < total);
    }

    // combine the two halves (VALU-rate, no LGKM); all lanes end with full sums
    s = sum_halves(s);
    #pragma unroll
    for (int k = 0; k < 4; k++) {
        acc2[k].x = sum_halves(acc2[k].x);
        acc2[k].y = sum_halves(acc2[k].y);
    }

    // epilogue split: half 0 -> channels f..f+3 (acc2[0..1]), half 1 -> f+4..f+7
    // (acc2[2..3]). Compile-time indices + cndmask (no runtime-indexed array).
    {
        float inv = 1.0f / (s + 1e-16f);
        unsigned fb = f + (unsigned)half * 4;
        bf16 ov[4];
        #pragma unroll
        for (int kk = 0; kk < 2; kk++) {
            floatx2 a = half ? acc2[2 + kk] : acc2[kk];
            float v0 = a.x * inv + bias[fb + 2 * kk];
            float v1 = a.y * inv + bias[fb + 2 * kk + 1];
            if (do_gelu) { v0 = gelu_f(v0); v1 = gelu_f(v1); }
            ov[2 * kk]     = f2b(v0);
            ov[2 * kk + 1] = f2b(v1);
        }
        *(short4v*)(out + ((unsigned)i * 256u + fb)) = *(const short4v*)ov;
    }
}

// ---------------- shared head-layer body (block = one (graph, 64-col chunk)) ----------------
__device__ __forceinline__ void head_body(const bf16* __restrict__ inB,
                                          const float* __restrict__ inF,
                                          const float* __restrict__ W,
                                          const float* __restrict__ bias,
                                          float* __restrict__ out,
                                          int K, int N, long long row_stride, int act,
                                          int g, int chunk, float* zin, float* red) {
    int t = threadIdx.x;
    int nc = t & 63;
    int kq = t >> 6;
    int n = chunk * 64 + nc;
    for (int k = t; k < K; k += 256)
        zin[k] = inB ? b2f(inB[(size_t)g * row_stride + k])
                     : inF[(size_t)g * row_stride + k];
    __syncthreads();
    const int klen = K >> 2;
    const int kb = kq * klen;
    float acc = 0.f;
    #pragma unroll 8
    for (int k = 0; k < klen; k++)
        acc = fmaf(zin[kb + k], W[(size_t)(kb + k) * N + n], acc);
    red[t] = acc;
    __syncthreads();
    if (kq == 0) {
        float v = red[nc] + red[nc + 64] + red[nc + 128] + red[nc + 192] + bias[n];
        if (act) v = gelu_f(v);
        out[(size_t)g * N + n] = v;
    }
}

// ---------------- fused: pool stage 1 (blocks 0..511) + head lin1 (512..1535) ----------------
__global__ __launch_bounds__(256) void k_pe1(const bf16* __restrict__ hb,
                                             float* __restrict__ part,
                                             const float* __restrict__ lin1w,
                                             const float* __restrict__ lin1b,
                                             float* __restrict__ t1, int PG) {
    __shared__ float zin[256];
    __shared__ float red[256];
    int bx = blockIdx.x;
    if (bx < 512) {
        int g = bx >> 3, p = bx & 7, c = threadIdx.x;
        int rows_per = PG / 8;
        const bf16* base = hb + ((size_t)g * PG + (size_t)p * rows_per) * 256;
        float acc = 0.f;
        for (int r = 0; r < rows_per; r++) acc += b2f(base[(size_t)r * 256 + c]);
        part[((size_t)g * 8 + p) * 256 + c] = acc;
    } else {
        int b = bx - 512;
        head_body(hb, nullptr, lin1w, lin1b, t1, 256, 1024,
                  (long long)PG * 256, 1, b >> 4, b & 15, zin, red);
    }
}

// ---------------- fused: pool stage 2 (blocks 0..63) + head lin2 (64..319) ----------------
__global__ __launch_bounds__(256) void k_pe2(const float* __restrict__ part,
                                             float* __restrict__ outPool, int PG,
                                             const float* __restrict__ t1,
                                             const float* __restrict__ lin2w,
                                             const float* __restrict__ lin2b,
                                             float* __restrict__ t2) {
    __shared__ float zin[1024];
    __shared__ float red[256];
    int bx = blockIdx.x;
    if (bx < 64) {
        int g = bx, c = threadIdx.x;
        float acc = 0.f;
        for (int p = 0; p < 8; p++) acc += part[((size_t)g * 8 + p) * 256 + c];
        outPool[g * 256 + c] = acc / (float)PG;
    } else {
        int b = bx - 64;
        head_body(nullptr, t1, lin2w, lin2b, t2, 1024, 256,
                  1024, 0, b >> 2, b & 3, zin, red);
    }
}

// ---------------- final head layer ----------------
__global__ __launch_bounds__(256) void k_fin(const float* __restrict__ t2,
                                             const float* __restrict__ finw,
                                             const float* __restrict__ finb,
                                             float* __restrict__ out) {
    __shared__ float zin[256];
    __shared__ float red[256];
    head_body(nullptr, t2, finw, finb, out, 256, 512,
              256, 0, blockIdx.x, blockIdx.y, zin, red);
}

extern "C" void kernel_launch(void* const* d_in, const int* in_sizes, int n_in,
                              void* d_out, int out_size, void* d_ws, size_t ws_size,
                              hipStream_t stream) {
    const float* x     = (const float*)d_in[0];
    const int*   ei    = (const int*)d_in[1];
    const float* w1_l  = (const float*)d_in[4];
    const float* b1_l  = (const float*)d_in[5];
    const float* w1_r  = (const float*)d_in[6];
    const float* b1_r  = (const float*)d_in[7];
    const float* att1  = (const float*)d_in[8];
    const float* bias1 = (const float*)d_in[9];
    const float* w2_l  = (const float*)d_in[10];
    const float* b2_l  = (const float*)d_in[11];
    const float* w2_r  = (const float*)d_in[12];
    const float* b2_r  = (const float*)d_in[13];
    const float* att2  = (const float*)d_in[14];
    const float* bias2 = (const float*)d_in[15];
    const float* lin1w = (const float*)d_in[16];
    const float* lin1b = (const float*)d_in[17];
    const float* lin2w = (const float*)d_in[18];
    const float* lin2b = (const float*)d_in[19];
    const float* finw  = (const float*)d_in[20];
    const float* finb  = (const float*)d_in[21];

    const int N  = in_sizes[0] / 256;   // 32768
    const int E  = in_sizes[1] / 2;     // 524288
    const int NG = 64;
    const int PG = N / NG;              // 512

    // workspace layout (~58 MiB)
    char* ws = (char*)d_ws;
    size_t off = 0;
    bf16* xlr = (bf16*)(ws + off); off += (size_t)N * 512 * 2;    // 32 MiB [xl|xr]
    bf16* hb  = (bf16*)(ws + off); off += (size_t)N * 256 * 2;    // 16 MiB (h1 then h2)
    bf16* wt  = (bf16*)(ws + off); off += 2 * 512 * 256 * 2;      // 512 KiB both layers' Wt
    int* cnt  = (int*)(ws + off); off += (size_t)N * 4;           // in-degree
    int* col  = (int*)(ws + off); off += (size_t)N * 64 * 4;      // 8 MiB bucket CSR
    float* pws = (float*)(ws + off); off += (size_t)NG * 8 * 256 * 4;  // pool partials
    float* t1  = (float*)(ws + off); off += (size_t)NG * 1024 * 4;
    float* t2  = (float*)(ws + off); off += (size_t)NG * 256 * 4;

    // bf16 copy of x aliases hb: dead until k_agg writes h1 (strictly after GEMM1 reads xb)
    bf16* xb = hb;

    const int* srcv = ei;
    const int* dstv = ei + E;

    // --- pre-pass: weight transposes + x->bf16 + cnt=0 (one launch, no memset) ---
    k_tr<<<1024 + 1024 + 128, 256, 0, stream>>>(w1_l, w1_r, w2_l, w2_r, wt, x, xb, cnt);

    // --- bucket scatter + layer-1 GEMM (union launch, scatter hidden under MFMA) ---
    k_scatter_gemm<<<512 + 1024, 256, 0, stream>>>(srcv, dstv, cnt, col, E,
                                                   xb, wt, b1_l, b1_r, xlr, 256);
    k_agg<<<N / 2, 128, 0, stream>>>(xlr, att1, cnt, col, bias1, hb, 1);  // + GELU

    // --- layer 2 (A = h1 bf16) ---
    dim3 gg(4, N / 128);
    k_gemm2<<<gg, 256, 0, stream>>>(hb, wt + 512 * 256, b2_l, b2_r, xlr, 256);
    k_agg<<<N / 2, 128, 0, stream>>>(xlr, att2, cnt, col, bias2, hb, 0);  // h2

    float* outp = (float*)d_out;
    // --- pool1 + head lin1 (one launch) ---
    k_pe1<<<512 + 1024, 256, 0, stream>>>(hb, pws, lin1w, lin1b, t1, PG);
    // --- pool2 (-> d_out[64*512..]) + head lin2 (one launch) ---
    k_pe2<<<64 + 256, 256, 0, stream>>>(pws, outp + 64 * 512, PG, t1, lin2w, lin2b, t2);
    // --- final head layer -> d_out[0..64*512) ---
    dim3 gf(NG, 512 / 64);
    k_fin<<<gf, 256, 0, stream>>>(t2, finw, finb, outp);
}

// Round 11
// 291.844 us; speedup vs baseline: 1.1368x; 1.1368x over previous
//
#include <hip/hip_runtime.h>
#include <hip/hip_bf16.h>
#include <stdint.h>

typedef __attribute__((ext_vector_type(8))) short short8;
typedef __attribute__((ext_vector_type(4))) short short4v;
typedef __attribute__((ext_vector_type(4))) float floatx4;
typedef __attribute__((ext_vector_type(2))) float floatx2;
typedef __attribute__((ext_vector_type(2))) int intx2;
typedef __hip_bfloat16 bf16;

__device__ __forceinline__ float b2f(bf16 v) { return __bfloat162float(v); }
__device__ __forceinline__ bf16 f2b(float v) { return __float2bfloat16(v); }
__device__ __forceinline__ float gelu_f(float v) {
    return 0.5f * v * (1.0f + erff(v * 0.70710678118654752f));
}
// two packed bf16 (one dword) -> two fp32, exact (<<16)
__device__ __forceinline__ floatx2 cvt2(unsigned v) {
    floatx2 r;
    r.x = __uint_as_float(v << 16);
    r.y = __uint_as_float(v & 0xffff0000u);
    return r;
}
// VALU-rate cross-lane add via DPP (no LGKM). CTRL: 0xB1=quad xor1, 0x4E=quad xor2,
// 0x141=row_half_mirror (cross-quad within 8-lane group; groups are 8-aligned).
template <int CTRL>
__device__ __forceinline__ float dpp_add(float v) {
    int x = __builtin_amdgcn_update_dpp(0, __float_as_int(v), CTRL, 0xf, 0xf, true);
    return v + __int_as_float(x);
}
// full-wave half sum at VALU rate: v[l] + v[l^32] for every lane.
__device__ __forceinline__ float sum_halves(float v) {
#if __has_builtin(__builtin_amdgcn_permlane32_swap)
    intx2 r = __builtin_amdgcn_permlane32_swap(__float_as_int(v), __float_as_int(v),
                                               false, false);
    return __int_as_float(r.x) + __int_as_float(r.y);
#else
    return v + __shfl_xor(v, 32, 64);
#endif
}

#define GLD_LDS16(gptr, lptr) \
  __builtin_amdgcn_global_load_lds((const __attribute__((address_space(1))) void*)(gptr), \
                                   (__attribute__((address_space(3))) void*)(lptr), 16, 0, 0)

// NOTE (R12): cooperative grid.sync() costs ~60us each here -- never fuse via grid.sync.
// NOTE (R15): GEMM LDS conflicts: fragment reads, fixed by XOR-swizzled 16B chunks
// (physical slot = logical ^ (row&7)); global_load_lds dest is linear, so swizzle the
// SOURCE k-offset.
// NOTE (R16): x pre-converted to bf16; GEMM = bf16 global_load_lds path; GEMM epilogue
// in two 64-row halves -> LDS exactly 32 KB.
// NOTE (R17/R20b, FAILED): extra per-lane state in k_agg loop kills occupancy/ILP.
// NOTE (R18, FAILED): node-grain work-steal = 32768 same-address atomics = 460us wall.
// NOTE (R19): 128-thread blocks; k_agg is instruction-issue-bound (VALU ~74%).
// NOTE (R21): leaky=max(u,0.2u); att pre-scaled by log2e -> raw v_exp_f32. KEEP.
// NOTE (R22/R23): bucket CSR (atomic return IS the slot) deletes scan/rank; scatter
// MUST stay overlapped with GEMM1 (standalone = 49us exposed latency). KEEP.
// NOTE (R24/R25, FAILED-codegen): lambdas capturing ARRAYS by reference (or passing
// register arrays by pointer) force allocas -> AMDGPU promote-alloca puts 32B/thread
// in LDS (LDS_Block_Size=4096, 1.97M bank conflicts, VALU 74->49%). In k_agg: NO
// lambdas, NO addressable arrays. R26: all state is individually named values, body
// is a textual macro. Same schedule as R24 (2x unroll, 4/4 epilogue split).

// ---------------- pre-pass: weight transposes (0..1023) + x->bf16 (1024..2047) + cnt=0 ----------------
__global__ void k_tr(const float* __restrict__ Wl1, const float* __restrict__ Wr1,
                     const float* __restrict__ Wl2, const float* __restrict__ Wr2,
                     bf16* __restrict__ Wt,
                     const float* __restrict__ x, bf16* __restrict__ xb,
                     int* __restrict__ cnt) {
    int bx = blockIdx.x;
    if (bx < 1024) {
        int r = bx & 255, half = (bx >> 8) & 1, layer = bx >> 9;
        int c = threadIdx.x;
        const float* W = layer ? (half ? Wr2 : Wl2) : (half ? Wr1 : Wl1);
        Wt[(size_t)(layer * 512 + half * 256 + c) * 256 + r] = f2b(W[r * 256 + c]);
    } else if (bx < 2048) {
        // x (32768x256 fp32) -> bf16, 32 contiguous floats per thread
        int b = bx - 1024;
        size_t base = ((size_t)b * 256 + threadIdx.x) * 32;
        const float4* xin = (const float4*)(x + base);
        #pragma unroll
        for (int q = 0; q < 4; q++) {
            float4 a = xin[2 * q];
            float4 c = xin[2 * q + 1];
            bf16 t[8] = {f2b(a.x), f2b(a.y), f2b(a.z), f2b(a.w),
                         f2b(c.x), f2b(c.y), f2b(c.z), f2b(c.w)};
            *(short8*)(xb + base + q * 8) = *(const short8*)t;
        }
    } else {
        // zero cnt (32768 ints; 128 blocks x 256 threads)
        cnt[(bx - 2048) * 256 + threadIdx.x] = 0;
    }
}

// ---------------- GEMM tile body: C[M,512] = A[M,K] @ Bt[512,K]^T + bias ----------------
// 128x128 tile, BK=64, XOR-swizzled LDS (physical 16B chunk = logical ^ (row&7)).
// bf16 A only (global_load_lds both operands). LDS = 32768 B exactly (5 blocks/CU).
__device__ __forceinline__ void gemm_body(const bf16* __restrict__ A,
                                          const bf16* __restrict__ Bt,
                                          const float* __restrict__ biasL,
                                          const float* __restrict__ biasR,
                                          bf16* __restrict__ C,
                                          int K, int m0, int n0,
                                          bf16* __restrict__ smem) {
    bf16* As = smem;
    bf16* Bs = smem + 8192;
    const int tid  = threadIdx.x;
    const int wave = tid >> 6;
    const int lane = tid & 63;
    const int quad = lane >> 4;
    const int l16  = lane & 15;
    const int wm = (wave & 1) * 64;
    const int wn = (wave >> 1) * 64;
    // source k-offset for swizzled global_load_lds staging (dest slot lane&7, row lane>>3)
    const int scole = ((lane & 7) ^ (lane >> 3)) * 8;
    const int srow  = lane >> 3;

    floatx4 acc[4][4] = {};

    for (int k0 = 0; k0 < K; k0 += 64) {
        #pragma unroll
        for (int i = 0; i < 4; i++) {
            int chunk = i * 4 + wave;                 // 16 chunks of 1 KB (8 rows) each
            int row = chunk * 8 + srow;
            GLD_LDS16(A + (size_t)(m0 + row) * K + k0 + scole,
                      (char*)As + chunk * 1024 + lane * 16);
            GLD_LDS16(Bt + (size_t)(n0 + row) * K + k0 + scole,
                      (char*)Bs + chunk * 1024 + lane * 16);
        }
        __syncthreads();
        #pragma unroll
        for (int ks = 0; ks < 2; ks++) {
            short8 af[4], bfr[4];
            int pk = ((ks * 4 + quad) ^ (l16 & 7)) * 8;   // swizzled fragment k-offset
            #pragma unroll
            for (int i = 0; i < 4; i++) {
                af[i]  = *(const short8*)&As[(wm + i * 16 + l16) * 64 + pk];
                bfr[i] = *(const short8*)&Bs[(wn + i * 16 + l16) * 64 + pk];
            }
            #pragma unroll
            for (int i = 0; i < 4; i++)
                #pragma unroll
                for (int j = 0; j < 4; j++)
                    acc[i][j] = __builtin_amdgcn_mfma_f32_16x16x32_bf16(af[i], bfr[j], acc[i][j], 0, 0, 0);
        }
        __syncthreads();
    }

    // C/D layout: col = lane&15, row = quad*4 + reg  [verified m89/m91]
    // Two 64-row halves through a 64x136 LDS buffer (fits in As+Bs region).
    float bvj[4];
    #pragma unroll
    for (int j = 0; j < 4; j++) {
        int gcol = n0 + wn + j * 16 + l16;
        bvj[j] = (gcol < 256) ? biasL[gcol] : biasR[gcol - 256];
    }
    #pragma unroll
    for (int h = 0; h < 2; h++) {
        if ((wave & 1) == h) {
            #pragma unroll
            for (int j = 0; j < 4; j++) {
                int lcol = wn + j * 16 + l16;
                #pragma unroll
                for (int i = 0; i < 4; i++)
                    #pragma unroll
                    for (int r = 0; r < 4; r++)
                        smem[(i * 16 + quad * 4 + r) * 136 + lcol] = f2b(acc[i][j][r] + bvj[j]);
            }
        }
        __syncthreads();
        {
            int rl = tid >> 4;
            int cs = (tid & 15) * 8;
            #pragma unroll
            for (int p = 0; p < 4; p++) {
                int row = p * 16 + rl;
                short8 v = *(const short8*)&smem[row * 136 + cs];
                *(short8*)(C + (size_t)(m0 + h * 64 + row) * 512 + n0 + cs) = v;
            }
        }
        if (h == 0) __syncthreads();
    }
}

// ---------------- union dispatch: bucket scatter + layer-1 GEMM (roles interleaved) ----------------
__global__ __launch_bounds__(256) void k_scatter_gemm(const int* __restrict__ src,
                                                      const int* __restrict__ dst,
                                                      int* __restrict__ cnt,
                                                      int* __restrict__ col, int E,
                                                      const bf16* __restrict__ A,
                                                      const bf16* __restrict__ Bt,
                                                      const float* __restrict__ biasL,
                                                      const float* __restrict__ biasR,
                                                      bf16* __restrict__ C, int K) {
    __shared__ bf16 smem[16384];
    int bx = blockIdx.x;
    int rem = bx % 3;
    if (rem == 2) {
        int g = (bx / 3) * 256 + threadIdx.x;
        if (g * 4 < E) {
            int4 d = ((const int4*)dst)[g];
            int4 s = ((const int4*)src)[g];
            int rk;
            rk = atomicAdd(&cnt[d.x], 1); if (rk < 64) col[(d.x << 6) + rk] = s.x;
            rk = atomicAdd(&cnt[d.y], 1); if (rk < 64) col[(d.y << 6) + rk] = s.y;
            rk = atomicAdd(&cnt[d.z], 1); if (rk < 64) col[(d.z << 6) + rk] = s.z;
            rk = atomicAdd(&cnt[d.w], 1); if (rk < 64) col[(d.w << 6) + rk] = s.w;
        }
    } else {
        int gid = (bx / 3) * 2 + rem;
        int n0 = (gid & 3) * 128;
        int m0 = (gid >> 2) * 128;
        gemm_body(A, Bt, biasL, biasR, C, K, m0, n0, smem);
    }
}

// ---------------- standalone GEMM (layer 2, bf16 A) ----------------
__global__ __launch_bounds__(256) void k_gemm2(const bf16* __restrict__ A,
                                               const bf16* __restrict__ Bt,
                                               const float* __restrict__ biasL,
                                               const float* __restrict__ biasR,
                                               bf16* __restrict__ C, int K) {
    __shared__ bf16 smem[16384];
    gemm_body(A, Bt, biasL, biasR, C, K, blockIdx.y * 128, blockIdx.x * 128, smem);
}

// per-item body for k_agg: all operands are NAMED values (no arrays, no lambdas --
// see R24/R25 note). G is a uint4; VALID a bool.
#define AGG_PROC(G, VALID)                                                        \
    {                                                                             \
        floatx2 xv0 = cvt2((G).x), xv1 = cvt2((G).y),                             \
                xv2 = cvt2((G).z), xv3 = cvt2((G).w);                             \
        floatx2 l2 = {0.f, 0.f};                                                  \
        floatx2 u, lr;                                                            \
        u = xv0 + xrv0; lr = __builtin_elementwise_max(u, u * c02); l2 += lr * attv0; \
        u = xv1 + xrv1; lr = __builtin_elementwise_max(u, u * c02); l2 += lr * attv1; \
        u = xv2 + xrv2; lr = __builtin_elementwise_max(u, u * c02); l2 += lr * attv2; \
        u = xv3 + xrv3; lr = __builtin_elementwise_max(u, u * c02); l2 += lr * attv3; \
        float l = l2.x + l2.y;                                                    \
        l = dpp_add<0xB1>(l);                                                     \
        l = dpp_add<0x4E>(l);                                                     \
        l = dpp_add<0x141>(l);                                                    \
        float p;                                                                  \
        asm("v_exp_f32 %0, %1" : "=v"(p) : "v"(l));                               \
        p = (VALID) ? p : 0.f;                                                    \
        s += p;                                                                   \
        floatx2 p2 = {p, p};                                                      \
        a0 += p2 * xv0; a1 += p2 * xv1; a2 += p2 * xv2; a3 += p2 * xv3;           \
    }

// ---------------- GATv2 aggregation: half-wave per edge, 8 ch/lane, packed fp32 math ----------
// 128-thread blocks, one wave per dst node. Lanes 0-31 = item a, 32-63 = item b of each
// pair. Within a half: 8 lanes per head (hl>>3), 8 channels per lane ((hl&7)*8).
// Item 0 = self-loop. Bucket CSR: node i's in-edges at col[i*64 .. i*64+deg).
// Max-free softmax (logits bounded). leaky = max(u, 0.2u); att pre-scaled by log2(e)
// so p = v_exp_f32(l) = e^logit. Reduce via DPP; half-combine via permlane32_swap.
// R26: 2x unroll, all-named-values body (no arrays/lambdas), 4/4 epilogue split.
__global__ __launch_bounds__(128) void k_agg(const bf16* __restrict__ xlr,
                                             const float* __restrict__ att,
                                             const int* __restrict__ cnt,
                                             const int* __restrict__ col,
                                             const float* __restrict__ bias,
                                             bf16* __restrict__ out, int do_gelu) {
    int wave = threadIdx.x >> 6, lane = threadIdx.x & 63;
    int i = blockIdx.x * 2 + wave;
    int hl = lane & 31;
    int half = lane >> 5;
    unsigned f = (hl >> 3) * 64 + (hl & 7) * 8;

    const float LOG2E = 1.4426950408889634f;
    const floatx2 c02 = {0.2f, 0.2f};
    floatx4 aa0 = *(const floatx4*)(att + f);
    floatx4 aa1 = *(const floatx4*)(att + f + 4);
    floatx2 attv0 = (floatx2){LOG2E * aa0[0], LOG2E * aa0[1]};
    floatx2 attv1 = (floatx2){LOG2E * aa0[2], LOG2E * aa0[3]};
    floatx2 attv2 = (floatx2){LOG2E * aa1[0], LOG2E * aa1[1]};
    floatx2 attv3 = (floatx2){LOG2E * aa1[2], LOG2E * aa1[3]};
    uint4 rv = *(const uint4*)(xlr + ((unsigned)i * 512u + 256u + f));
    floatx2 xrv0 = cvt2(rv.x), xrv1 = cvt2(rv.y), xrv2 = cvt2(rv.z), xrv3 = cvt2(rv.w);

    int deg = cnt[i];
    deg = deg > 64 ? 64 : deg;
    int e0 = i << 6;
    int total = 1 + deg;   // self + in-edges

    float s = 0.f;
    floatx2 a0 = {0.f, 0.f}, a1 = {0.f, 0.f}, a2 = {0.f, 0.f}, a3 = {0.f, 0.f};

    // 2x-unrolled pair loop: named uint4 buffers swap roles (no rotation movs).
    // Data prefetch 1 pair ahead, index 2 pairs ahead (same depth as R19-R23).
    // item t = base + {half, 2+half, ...}; t==0 is self-loop; OOB clamps to i.
    int sA = (half == 1 && total > 1) ? col[e0] : i;           // item(half)
    uint4 gA = *(const uint4*)(xlr + ((unsigned)sA * 512u + f));
    int tB = 2 + half;
    int sB = (tB < total) ? col[e0 + tB - 1] : i;              // item(2+half)
    uint4 gB;

    for (int base = 0; base < total; base += 4) {
        gB = *(const uint4*)(xlr + ((unsigned)sB * 512u + f));  // pair+1 data
        int tA = base + 4 + half;                               // pair+2 idx (t>0 always)
        sA = (tA < total) ? col[e0 + tA - 1] : i;
        AGG_PROC(gA, (base + half) < total);
        gA = *(const uint4*)(xlr + ((unsigned)sA * 512u + f));  // pair+2 data
        int tB2 = base + 6 + half;                              // pair+3 idx
        sB = (tB2 < total) ? col[e0 + tB2 - 1] : i;
        AGG_PROC(gB, (base + 2 + half) < total);
    }

    // combine the two halves (VALU-rate, no LGKM); all lanes end with full sums
    s = sum_halves(s);
    a0.x = sum_halves(a0.x); a0.y = sum_halves(a0.y);
    a1.x = sum_halves(a1.x); a1.y = sum_halves(a1.y);
    a2.x = sum_halves(a2.x); a2.y = sum_halves(a2.y);
    a3.x = sum_halves(a3.x); a3.y = sum_halves(a3.y);

    // epilogue split: half 0 -> channels f..f+3 (a0,a1), half 1 -> f+4..f+7 (a2,a3)
    {
        float inv = 1.0f / (s + 1e-16f);
        unsigned fb = f + (unsigned)half * 4;
        floatx2 e0v = half ? a2 : a0;
        floatx2 e1v = half ? a3 : a1;
        float v0 = e0v.x * inv + bias[fb];
        float v1 = e0v.y * inv + bias[fb + 1];
        float v2 = e1v.x * inv + bias[fb + 2];
        float v3 = e1v.y * inv + bias[fb + 3];
        if (do_gelu) {
            v0 = gelu_f(v0); v1 = gelu_f(v1); v2 = gelu_f(v2); v3 = gelu_f(v3);
        }
        bf16 ov[4] = {f2b(v0), f2b(v1), f2b(v2), f2b(v3)};
        *(short4v*)(out + ((unsigned)i * 256u + fb)) = *(const short4v*)ov;
    }
}

// ---------------- shared head-layer body (block = one (graph, 64-col chunk)) ----------------
__device__ __forceinline__ void head_body(const bf16* __restrict__ inB,
                                          const float* __restrict__ inF,
                                          const float* __restrict__ W,
                                          const float* __restrict__ bias,
                                          float* __restrict__ out,
                                          int K, int N, long long row_stride, int act,
                                          int g, int chunk, float* zin, float* red) {
    int t = threadIdx.x;
    int nc = t & 63;
    int kq = t >> 6;
    int n = chunk * 64 + nc;
    for (int k = t; k < K; k += 256)
        zin[k] = inB ? b2f(inB[(size_t)g * row_stride + k])
                     : inF[(size_t)g * row_stride + k];
    __syncthreads();
    const int klen = K >> 2;
    const int kb = kq * klen;
    float acc = 0.f;
    #pragma unroll 8
    for (int k = 0; k < klen; k++)
        acc = fmaf(zin[kb + k], W[(size_t)(kb + k) * N + n], acc);
    red[t] = acc;
    __syncthreads();
    if (kq == 0) {
        float v = red[nc] + red[nc + 64] + red[nc + 128] + red[nc + 192] + bias[n];
        if (act) v = gelu_f(v);
        out[(size_t)g * N + n] = v;
    }
}

// ---------------- fused: pool stage 1 (blocks 0..511) + head lin1 (512..1535) ----------------
__global__ __launch_bounds__(256) void k_pe1(const bf16* __restrict__ hb,
                                             float* __restrict__ part,
                                             const float* __restrict__ lin1w,
                                             const float* __restrict__ lin1b,
                                             float* __restrict__ t1, int PG) {
    __shared__ float zin[256];
    __shared__ float red[256];
    int bx = blockIdx.x;
    if (bx < 512) {
        int g = bx >> 3, p = bx & 7, c = threadIdx.x;
        int rows_per = PG / 8;
        const bf16* base = hb + ((size_t)g * PG + (size_t)p * rows_per) * 256;
        float acc = 0.f;
        for (int r = 0; r < rows_per; r++) acc += b2f(base[(size_t)r * 256 + c]);
        part[((size_t)g * 8 + p) * 256 + c] = acc;
    } else {
        int b = bx - 512;
        head_body(hb, nullptr, lin1w, lin1b, t1, 256, 1024,
                  (long long)PG * 256, 1, b >> 4, b & 15, zin, red);
    }
}

// ---------------- fused: pool stage 2 (blocks 0..63) + head lin2 (64..319) ----------------
__global__ __launch_bounds__(256) void k_pe2(const float* __restrict__ part,
                                             float* __restrict__ outPool, int PG,
                                             const float* __restrict__ t1,
                                             const float* __restrict__ lin2w,
                                             const float* __restrict__ lin2b,
                                             float* __restrict__ t2) {
    __shared__ float zin[1024];
    __shared__ float red[256];
    int bx = blockIdx.x;
    if (bx < 64) {
        int g = bx, c = threadIdx.x;
        float acc = 0.f;
        for (int p = 0; p < 8; p++) acc += part[((size_t)g * 8 + p) * 256 + c];
        outPool[g * 256 + c] = acc / (float)PG;
    } else {
        int b = bx - 64;
        head_body(nullptr, t1, lin2w, lin2b, t2, 1024, 256,
                  1024, 0, b >> 2, b & 3, zin, red);
    }
}

// ---------------- final head layer ----------------
__global__ __launch_bounds__(256) void k_fin(const float* __restrict__ t2,
                                             const float* __restrict__ finw,
                                             const float* __restrict__ finb,
                                             float* __restrict__ out) {
    __shared__ float zin[256];
    __shared__ float red[256];
    head_body(nullptr, t2, finw, finb, out, 256, 512,
              256, 0, blockIdx.x, blockIdx.y, zin, red);
}

extern "C" void kernel_launch(void* const* d_in, const int* in_sizes, int n_in,
                              void* d_out, int out_size, void* d_ws, size_t ws_size,
                              hipStream_t stream) {
    const float* x     = (const float*)d_in[0];
    const int*   ei    = (const int*)d_in[1];
    const float* w1_l  = (const float*)d_in[4];
    const float* b1_l  = (const float*)d_in[5];
    const float* w1_r  = (const float*)d_in[6];
    const float* b1_r  = (const float*)d_in[7];
    const float* att1  = (const float*)d_in[8];
    const float* bias1 = (const float*)d_in[9];
    const float* w2_l  = (const float*)d_in[10];
    const float* b2_l  = (const float*)d_in[11];
    const float* w2_r  = (const float*)d_in[12];
    const float* b2_r  = (const float*)d_in[13];
    const float* att2  = (const float*)d_in[14];
    const float* bias2 = (const float*)d_in[15];
    const float* lin1w = (const float*)d_in[16];
    const float* lin1b = (const float*)d_in[17];
    const float* lin2w = (const float*)d_in[18];
    const float* lin2b = (const float*)d_in[19];
    const float* finw  = (const float*)d_in[20];
    const float* finb  = (const float*)d_in[21];

    const int N  = in_sizes[0] / 256;   // 32768
    const int E  = in_sizes[1] / 2;     // 524288
    const int NG = 64;
    const int PG = N / NG;              // 512

    // workspace layout (~58 MiB)
    char* ws = (char*)d_ws;
    size_t off = 0;
    bf16* xlr = (bf16*)(ws + off); off += (size_t)N * 512 * 2;    // 32 MiB [xl|xr]
    bf16* hb  = (bf16*)(ws + off); off += (size_t)N * 256 * 2;    // 16 MiB (h1 then h2)
    bf16* wt  = (bf16*)(ws + off); off += 2 * 512 * 256 * 2;      // 512 KiB both layers' Wt
    int* cnt  = (int*)(ws + off); off += (size_t)N * 4;           // in-degree
    int* col  = (int*)(ws + off); off += (size_t)N * 64 * 4;      // 8 MiB bucket CSR
    float* pws = (float*)(ws + off); off += (size_t)NG * 8 * 256 * 4;  // pool partials
    float* t1  = (float*)(ws + off); off += (size_t)NG * 1024 * 4;
    float* t2  = (float*)(ws + off); off += (size_t)NG * 256 * 4;

    // bf16 copy of x aliases hb: dead until k_agg writes h1 (strictly after GEMM1 reads xb)
    bf16* xb = hb;

    const int* srcv = ei;
    const int* dstv = ei + E;

    // --- pre-pass: weight transposes + x->bf16 + cnt=0 (one launch, no memset) ---
    k_tr<<<1024 + 1024 + 128, 256, 0, stream>>>(w1_l, w1_r, w2_l, w2_r, wt, x, xb, cnt);

    // --- bucket scatter + layer-1 GEMM (union launch, scatter hidden under MFMA) ---
    k_scatter_gemm<<<512 + 1024, 256, 0, stream>>>(srcv, dstv, cnt, col, E,
                                                   xb, wt, b1_l, b1_r, xlr, 256);
    k_agg<<<N / 2, 128, 0, stream>>>(xlr, att1, cnt, col, bias1, hb, 1);  // + GELU

    // --- layer 2 (A = h1 bf16) ---
    dim3 gg(4, N / 128);
    k_gemm2<<<gg, 256, 0, stream>>>(hb, wt + 512 * 256, b2_l, b2_r, xlr, 256);
    k_agg<<<N / 2, 128, 0, stream>>>(xlr, att2, cnt, col, bias2, hb, 0);  // h2

    float* outp = (float*)d_out;
    // --- pool1 + head lin1 (one launch) ---
    k_pe1<<<512 + 1024, 256, 0, stream>>>(hb, pws, lin1w, lin1b, t1, PG);
    // --- pool2 (-> d_out[64*512..]) + head lin2 (one launch) ---
    k_pe2<<<64 + 256, 256, 0, stream>>>(pws, outp + 64 * 512, PG, t1, lin2w, lin2b, t2);
    // --- final head layer -> d_out[0..64*512) ---
    dim3 gf(NG, 512 / 64);
    k_fin<<<gf, 256, 0, stream>>>(t2, finw, finb, outp);
}